// Round 4
// 377.659 us; speedup vs baseline: 1.0399x; 1.0399x over previous
//
#include <hip/hip_runtime.h>
#include <math.h>

#define F_DIM 32
#define A_DIM 8
#define T_DIM 400

// clang vector types — required for __builtin_nontemporal_load/store
// (HIP float4/float2 are structs and are rejected by the builtin).
typedef float        f32x2 __attribute__((ext_vector_type(2)));
typedef float        f32x4 __attribute__((ext_vector_type(4)));
typedef unsigned int u32x4 __attribute__((ext_vector_type(4)));
typedef unsigned short u16x4 __attribute__((ext_vector_type(4)));

static __device__ __forceinline__ float az_step()     { return 0.78539816339744830962f; } // pi/4
static __device__ __forceinline__ float pi_f()        { return 3.14159265358979323846f; }
static __device__ __forceinline__ float inv_sin_om()  { return 1.41421356237309504880f; } // 1/sin(pi/4)
static __device__ __forceinline__ float four_ov_pi()  { return 1.27323954473516268615f; }

// bf16 pair unpack from a packed u32 (little-endian: low half = even feature)
static __device__ __forceinline__ float blo(unsigned int u) { return __uint_as_float(u << 16); }
static __device__ __forceinline__ float bhi(unsigned int u) { return __uint_as_float(u & 0xffff0000u); }

static __device__ __forceinline__ unsigned short f2b(float f) {
    unsigned int x = __float_as_uint(f);
    unsigned int r = (x + 0x7FFFu + ((x >> 16) & 1u)) >> 16; // round-to-nearest-even
    return (unsigned short)r;
}

// ---------------- transpose+quantize (F, M) f32 -> (M, F) bf16 ----------------
// NT loads on src: grid f32 is read exactly once; keep it from evicting the
// bf16 table (which interp re-reads) out of L2/L3.
__global__ __launch_bounds__(256) void transpose_bf16_kernel(const float* __restrict__ src,
                                                             unsigned short* __restrict__ dst,
                                                             int M) {
    __shared__ float t[F_DIM][257]; // stride 257: bank = (f+m)&31, ~2-way max (free)
    const int m0 = blockIdx.x * 256;
    const int f  = threadIdx.x >> 3;        // 0..31
    const int ms = (threadIdx.x & 7) * 4;   // 0,4,...,28
#pragma unroll
    for (int it = 0; it < 8; ++it) {
        int m = ms + 32 * it;
        f32x4 v = __builtin_nontemporal_load((const f32x4*)(src + (size_t)f * M + m0 + m));
        t[f][m] = v.x; t[f][m + 1] = v.y; t[f][m + 2] = v.z; t[f][m + 3] = v.w;
    }
    __syncthreads();
    const int fi = (threadIdx.x & 7) * 4;   // 0,4,...,28
    const int mb = threadIdx.x >> 3;        // 0..31
#pragma unroll
    for (int it = 0; it < 8; ++it) {
        int m = mb + 32 * it;
        u16x4 o;
        o.x = f2b(t[fi][m]);
        o.y = f2b(t[fi + 1][m]);
        o.z = f2b(t[fi + 2][m]);
        o.w = f2b(t[fi + 3][m]);
        *(u16x4*)(dst + (size_t)(m0 + m) * F_DIM + fi) = o; // cached: interp re-reads this
    }
}

// ---------------- per-point parameter math (matches torch.bucketize / ref) ----------------
struct PtParams {
    int   base[4];   // (a_l,il0) (a_l,ir0) (a_r,il0) (a_r,ir0), element index incl. *F
    int   d1;        // (ir1-il1)*F  (0 or F)
    float wA[4];     // {w1*ul, w1*ur, w2*ul, w2*ur}
    float vl, vr;
};

static __device__ __forceinline__ PtParams compute_params(float x, float y, float d) {
    PtParams P;
    // axis 0
    int ir0 = (int)ceilf(x * 4.0f); if (ir0 > T_DIM - 1) ir0 = T_DIM - 1; if (ir0 < 0) ir0 = 0;
    int il0 = ir0 - 1; if (il0 < 0) il0 = 0;
    float dl0 = fmaxf(x - (float)il0 * 0.25f, 0.0f);
    float dr0 = fmaxf((float)ir0 * 0.25f - x, 0.0f);
    if (dl0 == 0.0f && dr0 == 0.0f) { dl0 = 1.0f; dr0 = 1.0f; }
    float inv0 = 1.0f / (dl0 + dr0);
    float ul = dr0 * inv0, ur = dl0 * inv0;
    // axis 1
    int ir1 = (int)ceilf(y * 4.0f); if (ir1 > T_DIM - 1) ir1 = T_DIM - 1; if (ir1 < 0) ir1 = 0;
    int il1 = ir1 - 1; if (il1 < 0) il1 = 0;
    float dl1 = fmaxf(y - (float)il1 * 0.25f, 0.0f);
    float dr1 = fmaxf((float)ir1 * 0.25f - y, 0.0f);
    if (dl1 == 0.0f && dr1 == 0.0f) { dl1 = 1.0f; dr1 = 1.0f; }
    float inv1 = 1.0f / (dl1 + dr1);
    P.vl = dr1 * inv1; P.vr = dl1 * inv1;
    // azimuth
    int k = (int)floorf((d + pi_f()) * four_ov_pi());
    if (k < 0) k = 0; if (k > A_DIM - 1) k = A_DIM - 1;
    int al = k, ar = (k + 1) & (A_DIM - 1);
    float theta = fmaxf(d - (-pi_f() + (float)k * az_step()), 0.0f);
    float w1 = sinf(az_step() - theta) * inv_sin_om();
    float w2 = sinf(theta) * inv_sin_om();
    P.wA[0] = w1 * ul; P.wA[1] = w1 * ur;
    P.wA[2] = w2 * ul; P.wA[3] = w2 * ur;
    P.base[0] = ((al * T_DIM + il0) * T_DIM + il1) * F_DIM;
    P.base[1] = ((al * T_DIM + ir0) * T_DIM + il1) * F_DIM;
    P.base[2] = ((ar * T_DIM + il0) * T_DIM + il1) * F_DIM;
    P.base[3] = ((ar * T_DIM + ir0) * T_DIM + il1) * F_DIM;
    P.d1 = (ir1 - il1) * F_DIM;
    return P;
}

// ---------------- main gather kernel (transposed bf16 table) ----------------
// 256 points/block. Phase 1: every thread computes params for its own point.
// Phase 2: 4 lanes per point; each lane owns 8 features and loads dwordx4
// (8 bf16) for the left row and right row of each of the 4 (az,x) bases.
// Per load instruction: 64 lanes x 16 B = 1 KB in 16 full 64-B segments.
// Output written directly with non-temporal stores (4 full 64-B lines per
// store instruction) -- no LDS staging, no second barrier.
__global__ __launch_bounds__(256, 4) void interp_kernel(const float* __restrict__ pos,
                                                        const float* __restrict__ dirs,
                                                        const unsigned short* __restrict__ Gt,
                                                        float* __restrict__ out, int N) {
    __shared__ int   s_base[256][4];
    __shared__ int   s_d1[256];
    __shared__ float s_wA[256][4];
    __shared__ float s_vl[256];
    __shared__ float s_vr[256];

    const int n0 = blockIdx.x * 256;
    const int t  = threadIdx.x;

    {
        int n = n0 + t;
        float x = 0.0f, y = 0.0f, d = 0.0f;
        if (n < N) {
            f32x2 p = __builtin_nontemporal_load(((const f32x2*)pos) + n);
            x = p.x; y = p.y;
            d = __builtin_nontemporal_load(dirs + n);
        }
        PtParams P = compute_params(x, y, d);
#pragma unroll
        for (int j = 0; j < 4; ++j) { s_base[t][j] = P.base[j]; s_wA[t][j] = P.wA[j]; }
        s_d1[t] = P.d1;
        s_vl[t] = P.vl; s_vr[t] = P.vr;
    }
    __syncthreads();

    const int wv  = t >> 6;        // wave 0..3
    const int ln  = t & 63;
    const int sub = ln >> 2;       // point-within-group 0..15
    const int fq  = (ln & 3) * 8;  // feature octet base: 0,8,16,24

#pragma unroll
    for (int it = 0; it < 4; ++it) {
        const int p = wv * 64 + it * 16 + sub;
        const int n = n0 + p;
        const float vl = s_vl[p], vr = s_vr[p];
        const int d1 = s_d1[p];
        float a0 = 0.f, a1 = 0.f, a2 = 0.f, a3 = 0.f;
        float a4 = 0.f, a5 = 0.f, a6 = 0.f, a7 = 0.f;
#pragma unroll
        for (int j = 0; j < 4; ++j) {
            const unsigned short* gp = Gt + (s_base[p][j] + fq);
            u32x4 L = *(const u32x4*)gp;          // features fq..fq+7, left y-row
            u32x4 R = *(const u32x4*)(gp + d1);   // same features, right y-row
            float w  = s_wA[p][j];
            float wl = w * vl, wr = w * vr;
            a0 = fmaf(wl, blo(L.x), a0); a0 = fmaf(wr, blo(R.x), a0);
            a1 = fmaf(wl, bhi(L.x), a1); a1 = fmaf(wr, bhi(R.x), a1);
            a2 = fmaf(wl, blo(L.y), a2); a2 = fmaf(wr, blo(R.y), a2);
            a3 = fmaf(wl, bhi(L.y), a3); a3 = fmaf(wr, bhi(R.y), a3);
            a4 = fmaf(wl, blo(L.z), a4); a4 = fmaf(wr, blo(R.z), a4);
            a5 = fmaf(wl, bhi(L.z), a5); a5 = fmaf(wr, bhi(R.z), a5);
            a6 = fmaf(wl, blo(L.w), a6); a6 = fmaf(wr, blo(R.w), a6);
            a7 = fmaf(wl, bhi(L.w), a7); a7 = fmaf(wr, bhi(R.w), a7);
        }
        if (n < N) {
            float* op = out + (size_t)fq * (size_t)N + n;
            __builtin_nontemporal_store(a0, op);
            __builtin_nontemporal_store(a1, op + (size_t)N);
            __builtin_nontemporal_store(a2, op + 2 * (size_t)N);
            __builtin_nontemporal_store(a3, op + 3 * (size_t)N);
            __builtin_nontemporal_store(a4, op + 4 * (size_t)N);
            __builtin_nontemporal_store(a5, op + 5 * (size_t)N);
            __builtin_nontemporal_store(a6, op + 6 * (size_t)N);
            __builtin_nontemporal_store(a7, op + 7 * (size_t)N);
        }
    }
}

// ---------------- fallback: direct gather from original layout ----------------
__global__ __launch_bounds__(256) void direct_kernel(const float* __restrict__ pos,
                                                     const float* __restrict__ dirs,
                                                     const float* __restrict__ grid,
                                                     float* __restrict__ out, int N) {
    int n = blockIdx.x * blockDim.x + threadIdx.x;
    if (n >= N) return;
    float2 p = ((const float2*)pos)[n];
    PtParams P = compute_params(p.x, p.y, dirs[n]);
    int b[4], d1 = P.d1 / F_DIM;
#pragma unroll
    for (int j = 0; j < 4; ++j) b[j] = P.base[j] / F_DIM;
    const int fstride = A_DIM * T_DIM * T_DIM;
    for (int f = 0; f < F_DIM; ++f) {
        const float* gf = grid + (size_t)f * fstride;
        float acc = 0.0f;
#pragma unroll
        for (int j = 0; j < 4; ++j) {
            float w = P.wA[j];
            acc = fmaf(w * P.vl, gf[b[j]],      acc);
            acc = fmaf(w * P.vr, gf[b[j] + d1], acc);
        }
        out[(size_t)f * N + n] = acc;
    }
}

extern "C" void kernel_launch(void* const* d_in, const int* in_sizes, int n_in,
                              void* d_out, int out_size, void* d_ws, size_t ws_size,
                              hipStream_t stream) {
    const float* pos  = (const float*)d_in[0];
    const float* dirs = (const float*)d_in[1];
    const float* grid = (const float*)d_in[2];
    float* out = (float*)d_out;
    const int N = in_sizes[1];

    const size_t needed = (size_t)A_DIM * T_DIM * T_DIM * F_DIM * sizeof(unsigned short);
    if (ws_size >= needed) {
        unsigned short* Gt = (unsigned short*)d_ws;
        const int M = A_DIM * T_DIM * T_DIM; // 1,280,000 — divisible by 256
        transpose_bf16_kernel<<<M / 256, 256, 0, stream>>>(grid, Gt, M);
        interp_kernel<<<(N + 255) / 256, 256, 0, stream>>>(pos, dirs, Gt, out, N);
    } else {
        direct_kernel<<<(N + 255) / 256, 256, 0, stream>>>(pos, dirs, grid, out, N);
    }
}